// Round 10
// baseline (221.609 us; speedup 1.0000x reference)
//
#include <hip/hip_runtime.h>
#include <hip/hip_fp16.h>
#include <math.h>

#define BB 8
#define HH 384
#define WW 768
#define HW (HH * WW)
#define NPIX (BB * HW)       // 2359296

#define NT 512           // fallback fused kernel threads
#define K2T 256          // K2 threads per block
#define TX 64
#define TY 16
#define HX (TX + 6)      // 70
#define HY (TY + 6)      // 22
#define LP 72            // LDS plane row stride (uint2 elements)
#define TILES_X (WW / TX)            // 12
#define TILES_Y (HH / TY)            // 24
#define NTILE (TILES_X * TILES_Y)    // 288 per image
#define GRID2 (NTILE * BB)           // 2304
#define NB1 (NPIX / 256)             // 9216 K1 blocks total (256 thr)
#define NB1H (NB1 / 2)               // 4608 per half-dispatch
#define K1TX 12                      // K1: 64x4 tiles, 12 x 96 per image

// 8-byte pair load with only 4-byte alignment guaranteed.
struct F2 { float x, y; };
__device__ __forceinline__ F2 ld2(const float* __restrict__ p) {
    return *(const F2*)p;
}

// ---------- exact bilinear (feeds binary occ -> must stay bit-stable) ----------
struct Bil { int x0, x1, y0, y1; float wx, wy; };

__device__ __forceinline__ Bil bilin_setup(float fx, float fy, int x, int y) {
    Bil s;
    float gx = fminf(fmaxf(fx + (float)x, 0.0f), (float)(WW - 1));
    float gy = fminf(fmaxf(fy + (float)y, 0.0f), (float)(HH - 1));
    float x0f = floorf(gx), y0f = floorf(gy);
    s.wx = gx - x0f;
    s.wy = gy - y0f;
    s.x0 = (int)x0f;
    s.y0 = (int)y0f;
    s.x1 = min(s.x0 + 1, WW - 1);
    s.y1 = min(s.y0 + 1, HH - 1);
    return s;
}

__device__ __forceinline__ float bilin(const float* __restrict__ pl, const Bil& s) {
    float v00 = pl[s.y0 * WW + s.x0];
    float v01 = pl[s.y0 * WW + s.x1];
    float v10 = pl[s.y1 * WW + s.x0];
    float v11 = pl[s.y1 * WW + s.x1];
    float iwx = 1.0f - s.wx, iwy = 1.0f - s.wy;
    return v00 * iwx * iwy + v01 * s.wx * iwy + v10 * iwx * s.wy + v11 * s.wx * s.wy;
}

// Paired-load bilin: BIT-IDENTICAL values to bilin() in all cases (r6 proof).
__device__ __forceinline__ float bilin2(const float* __restrict__ pl, const Bil& s) {
    int xb = min(s.x0, WW - 2);
    bool hi = s.x0 > xb;                       // only at the x==W-1 border
    F2 tp = ld2(pl + s.y0 * WW + xb);
    F2 bt = ld2(pl + s.y1 * WW + xb);
    float v00 = hi ? tp.y : tp.x;
    float v10 = hi ? bt.y : bt.x;
    float v01 = tp.y;
    float v11 = bt.y;
    float iwx = 1.0f - s.wx, iwy = 1.0f - s.wy;
    return v00 * iwx * iwy + v01 * s.wx * iwy + v10 * iwx * s.wy + v11 * s.wx * s.wy;
}

// ---------- fast bilinear (image gathers; loss-tolerant) ----------
struct FBil { int off; float wx, wy; };

__device__ __forceinline__ FBil fast_setup(float fx, float fy, int x, int y) {
    FBil s;
    float gx = fminf(fmaxf(fx + (float)x, 0.0f), (float)(WW - 1));
    float gy = fminf(fmaxf(fy + (float)y, 0.0f), (float)(HH - 1));
    int x0 = min((int)floorf(gx), WW - 2);
    int y0 = min((int)floorf(gy), HH - 2);
    s.wx = gx - (float)x0;
    s.wy = gy - (float)y0;
    s.off = y0 * WW + x0;
    return s;
}

__device__ __forceinline__ float fbil(const float* __restrict__ pl, const FBil& s) {
    const float* q = pl + s.off;
    float v00 = q[0], v01 = q[1], v10 = q[WW], v11 = q[WW + 1];
    float top = fmaf(s.wx, v01 - v00, v00);
    float bot = fmaf(s.wx, v11 - v10, v10);
    return fmaf(s.wy, bot - top, top);
}

// Paired-load fbil: identical arithmetic, 2 VMEM instead of 4.
__device__ __forceinline__ float fbil2(const float* __restrict__ pl, const FBil& s) {
    F2 t = ld2(pl + s.off);
    F2 b = ld2(pl + s.off + WW);
    float top = fmaf(s.wx, t.y - t.x, t.x);
    float bot = fmaf(s.wx, b.y - b.x, b.x);
    return fmaf(s.wy, bot - top, top);
}

__device__ __forceinline__ float gray255(float r, float g, float b) {
    return (0.2989f * r + 0.587f * g + 0.114f * b) * 255.0f;
}

__device__ __forceinline__ float robust04(float a) {
    // pow(|a| + 0.01, 0.4) via HW log2/exp2 (arg always > 0)
    float v = fabsf(a) + 0.01f;
    return __builtin_amdgcn_exp2f(0.4f * __builtin_amdgcn_logf(v));
}

struct __align__(8) Pair4 {
    __half2 fw;   // (inten1, inten2w)
    __half2 bw;   // (inten2, inten1w)
};

__device__ __forceinline__ float2 h2f(unsigned int u) {
    __half2 h;
    *reinterpret_cast<unsigned int*>(&h) = u;
    return __half22float2(h);
}

// Census tap on 4 scalars; single-rsq identity + shared rcp [validated r1/r2].
__device__ __forceinline__ void tap_eval4(float Vx, float Vy, float Vz, float Vw,
                                          float Cx, float Cy, float Cz, float Cw,
                                          float& dsf, float& dsb) {
    float u1 = Vx - Cx, u2 = Vy - Cy;
    float q1 = u1 * u1, q2 = u2 * u2;
    float a1 = q1 + 0.81f, a2 = q2 + 0.81f;
    float sf = __builtin_amdgcn_rsqf(a1 * a2);
    float hf = fmaf(q1, a2, q2 * a1);
    float d2f = fmaf(sf * sf, hf, -2.0f * ((u1 * u2) * sf));

    float w1 = Vz - Cz, w2 = Vw - Cw;
    float p1 = w1 * w1, p2 = w2 * w2;
    float b1 = p1 + 0.81f, b2 = p2 + 0.81f;
    float sb = __builtin_amdgcn_rsqf(b1 * b2);
    float hb = fmaf(p1, b2, p2 * b1);
    float d2b = fmaf(sb * sb, hb, -2.0f * ((w1 * w2) * sb));

    float denf = 0.1f + d2f, denb = 0.1f + d2b;
    float rr = __builtin_amdgcn_rcpf(denf * denb);
    dsf = fmaf(d2f * denb, rr, dsf);
    dsb = fmaf(d2b * denf, rr, dsb);
}

// ==================== K1: per-pixel warp/photo/occ, plane production ==========
// 1 px/thread, 64x4 tiles, 256-thread blocks (round-6 winner: 71.5 us).
// Launched as TWO half-grid dispatches (bbase = 0 / NB1H) so k2 becomes the
// longest dispatch and surfaces in rocprof top-5 (r9 instrumentation probe).
// img = gb&7 keeps image<->XCD affinity; paired 8B corner loads (round 6).
// pacc1 layout per block: [pf, pb, mf, mb]
__global__ __launch_bounds__(256) void k1_kernel(
        const float* __restrict__ img1, const float* __restrict__ img2,
        const float* __restrict__ ffw, const float* __restrict__ fbw,
        Pair4* __restrict__ planes, uchar2* __restrict__ masks,
        float* __restrict__ pacc1, float* __restrict__ occ_out, int bbase) {
    const int gb = blockIdx.x + bbase;        // global block id 0..9215
    const int img = gb & 7;
    const int t = gb >> 3;                    // 0..1151
    const int tyy = t / K1TX;                 // 4-row band 0..95
    const int txx = t - tyy * K1TX;
    const int x = txx * 64 + (threadIdx.x & 63);
    const int y = tyy * 4 + (threadIdx.x >> 6);
    const int p = y * WW + x;
    const int g = img * HW + p;

    const float* i1 = img1 + img * 3 * HW;
    const float* i2 = img2 + img * 3 * HW;
    const float* f1 = ffw + img * 2 * HW;
    const float* f2 = fbw + img * 2 * HW;

    float fx = f1[p], fy = f1[HW + p];
    float bx = f2[p], by = f2[HW + p];
    float a0 = i1[p], a1 = i1[HW + p], a2 = i1[2 * HW + p];
    float c0 = i2[p], c1 = i2[HW + p], c2 = i2[2 * HW + p];

    // image gathers: fast shared-base path (feeds losses only)
    FBil qf = fast_setup(fx, fy, x, y);
    FBil qb = fast_setup(bx, by, x, y);
    float w20 = fbil2(i2, qf);
    float w21 = fbil2(i2 + HW, qf);
    float w22 = fbil2(i2 + 2 * HW, qf);
    float w10 = fbil2(i1, qb);
    float w11 = fbil2(i1 + HW, qb);
    float w12 = fbil2(i1 + 2 * HW, qb);

    float v1 = gray255(a0, a1, a2);
    float v2 = gray255(c0, c1, c2);
    float v2w = gray255(w20, w21, w22);
    float v1w = gray255(w10, w11, w12);

    // flow gathers: exact path (feeds binary occ)
    Bil sf = bilin_setup(fx, fy, x, y);
    Bil sb = bilin_setup(bx, by, x, y);
    float wbx = bilin2(f2, sf), wby = bilin2(f2 + HW, sf);
    float wfx = bilin2(f1, sb), wfy = bilin2(f1 + HW, sb);

    float dfx = fx + wbx, dfy = fy + wby;
    float magf = dfx * dfx + dfy * dfy;
    float fmf = fx * fx + fy * fy + wbx * wbx + wby * wby;
    float occf = (magf > 0.01f * fmf + 0.5f) ? 1.0f : 0.0f;
    float mf = 1.0f - occf;

    float dbx = bx + wfx, dby = by + wfy;
    float magb = dbx * dbx + dby * dby;
    float fmb = bx * bx + by * by + wfx * wfx + wfy * wfy;
    float occb = (magb > 0.01f * fmb + 0.5f) ? 1.0f : 0.0f;
    float mb = 1.0f - occb;

    occ_out[g] = occf;
    masks[g] = make_uchar2((unsigned char)mf, (unsigned char)mb);
    Pair4 pr;
    pr.fw = __floats2half2_rn(v1, v2w);
    pr.bw = __floats2half2_rn(v2, v1w);
    planes[g] = pr;

    float s_pf = (robust04(a0 - w20) + robust04(a1 - w21) + robust04(a2 - w22)) * mf;
    float s_pb = (robust04(c0 - w10) + robust04(c1 - w11) + robust04(c2 - w12)) * mb;

    // block reduce 4 partials (4 waves)
    float s_mf = mf, s_mb = mb;
    for (int o = 32; o > 0; o >>= 1) {
        s_pf += __shfl_down(s_pf, o, 64);
        s_pb += __shfl_down(s_pb, o, 64);
        s_mf += __shfl_down(s_mf, o, 64);
        s_mb += __shfl_down(s_mb, o, 64);
    }
    __shared__ float red[4][4];
    const int wid = threadIdx.x >> 6;
    if ((threadIdx.x & 63) == 0) {
        red[wid][0] = s_pf; red[wid][1] = s_pb;
        red[wid][2] = s_mf; red[wid][3] = s_mb;
    }
    __syncthreads();
    if (threadIdx.x == 0) {
        float r0 = 0.f, r1 = 0.f, r2 = 0.f, r3 = 0.f;
        for (int i = 0; i < 4; ++i) {
            r0 += red[i][0]; r1 += red[i][1]; r2 += red[i][2]; r3 += red[i][3];
        }
        float* o = pacc1 + gb * 4;
        o[0] = r0; o[1] = r1; o[2] = r2; o[3] = r3;
    }
}

// ==================== K2: census over live pixels ============================
// PF/PB interleaved as uint2 in LDS: one ds_read_b64 per tap instead of two
// ds_read_b32 (r9; bit-identical data, halves LDS instruction count).
// 256-thread blocks, 4-segment ballot compaction. pacc2: [cf, cb]
__global__ __launch_bounds__(K2T) void k2_kernel(
        const Pair4* __restrict__ planes, const uchar2* __restrict__ masks,
        float* __restrict__ pacc2) {
    __shared__ uint2 PP[HY][LP];          // (fw bits, bw bits), 12.7 KB
    __shared__ unsigned short WORK[TY * TX];  // pix | mf<<10 | mb<<11
    __shared__ int wcnt[16];              // [segment 0..3][wave 0..3]
    __shared__ float red[4][2];

    const int img = blockIdx.x & 7;
    const int t = blockIdx.x >> 3;
    const int tyile = t / TILES_X;
    const int txile = t - tyile * TILES_X;
    const int gx0 = txile * TX - 3;
    const int gy0 = tyile * TY - 3;

    // ---- stage planes (coalesced 8B loads, direct uint2 LDS writes) ----
    const uint2* pl2 = (const uint2*)planes;
    for (int i = threadIdx.x; i < HX * HY; i += K2T) {
        int ly = i / HX;
        int lx = i - ly * HX;
        int gx = gx0 + lx;
        int gy = gy0 + ly;
        uint2 pr8 = make_uint2(0u, 0u);
        if (((unsigned)gx < (unsigned)WW) & ((unsigned)gy < (unsigned)HH)) {
            pr8 = pl2[img * HW + gy * WW + gx];
        }
        PP[ly][lx] = pr8;
    }
    __syncthreads();

    // ---- live-pixel compaction: 4 segments x 4 waves, ballot prefix ----
    const int lane = threadIdx.x & 63;
    const int wid = threadIdx.x >> 6;           // 0..3
    const unsigned long long lt = (1ull << lane) - 1ull;
    const int grow = img * HW + (tyile * TY) * WW + txile * TX;   // g of tile (0,0)
    int ntot;
    {
        bool lv[4];
        unsigned long long bl[4];
        unsigned short pb[4];
#pragma unroll
        for (int sg = 0; sg < 4; ++sg) {
            int pix = sg * K2T + threadIdx.x;
            uchar2 m = masks[grow + (pix >> 6) * WW + (pix & 63)];
            lv[sg] = (m.x | m.y) != 0;
            bl[sg] = __ballot(lv[sg]);
            pb[sg] = (unsigned short)(pix | (m.x ? 1024 : 0) | (m.y ? 2048 : 0));
            if (lane == 0) wcnt[sg * 4 + wid] = __popcll(bl[sg]);
        }
        __syncthreads();
        int base_[4] = {0, 0, 0, 0};
        ntot = 0;
        for (int k = 0; k < 16; ++k) {
            int v = wcnt[k];
#pragma unroll
            for (int sg = 0; sg < 4; ++sg)
                if (k < sg * 4 + wid) base_[sg] += v;
            ntot += v;
        }
#pragma unroll
        for (int sg = 0; sg < 4; ++sg)
            if (lv[sg]) WORK[base_[sg] + __popcll(bl[sg] & lt)] = pb[sg];
        __syncthreads();
    }

    // ---- 49-tap census over worklist; 1 ds_read_b64 per tap ----
    float s_cf = 0.f, s_cb = 0.f;
    for (int w = threadIdx.x; w < ntot; w += K2T) {
        int e = WORK[w];
        int pix = e & 1023;
        int r = pix >> 6, c = pix & 63;
        uint2 C = PP[3 + r][3 + c];
        float2 cf = h2f(C.x);
        float2 cb = h2f(C.y);
        float dsf = 0.f, dsb = 0.f;
#pragma unroll 1
        for (int dy = 0; dy < 7; ++dy) {
            const uint2* row = &PP[r + dy][c];
#pragma unroll
            for (int dx = 0; dx < 7; ++dx) {
                uint2 V = row[dx];
                float2 vf = h2f(V.x);
                float2 vb = h2f(V.y);
                tap_eval4(vf.x, vf.y, vb.x, vb.y, cf.x, cf.y, cb.x, cb.y, dsf, dsb);
            }
        }
        s_cf += robust04(dsf) * (float)((e >> 10) & 1);
        s_cb += robust04(dsb) * (float)((e >> 11) & 1);
    }

    // ---- reduce 2 partials across 4 waves ----
    for (int o = 32; o > 0; o >>= 1) {
        s_cf += __shfl_down(s_cf, o, 64);
        s_cb += __shfl_down(s_cb, o, 64);
    }
    if (lane == 0) {
        red[wid][0] = s_cf; red[wid][1] = s_cb;
    }
    __syncthreads();
    if (threadIdx.x == 0) {
        float r4 = 0.f, r5 = 0.f;
        for (int i = 0; i < 4; ++i) { r4 += red[i][0]; r5 += red[i][1]; }
        float* o = pacc2 + blockIdx.x * 2;
        o[0] = r4; o[1] = r5;
    }
}

__global__ __launch_bounds__(1024) void finalize2_kernel(
        const float* __restrict__ pacc1, const float* __restrict__ pacc2,
        float* __restrict__ out) {
    float s0 = 0.f, s1 = 0.f, s2 = 0.f, s3 = 0.f, s4 = 0.f, s5 = 0.f;
    for (int i = threadIdx.x; i < NB1; i += 1024) {
        const float* o = pacc1 + i * 4;
        s0 += o[0]; s1 += o[1]; s2 += o[2]; s3 += o[3];
    }
    for (int i = threadIdx.x; i < GRID2; i += 1024) {
        const float* o = pacc2 + i * 2;
        s4 += o[0]; s5 += o[1];
    }
    for (int o = 32; o > 0; o >>= 1) {
        s0 += __shfl_down(s0, o, 64);
        s1 += __shfl_down(s1, o, 64);
        s2 += __shfl_down(s2, o, 64);
        s3 += __shfl_down(s3, o, 64);
        s4 += __shfl_down(s4, o, 64);
        s5 += __shfl_down(s5, o, 64);
    }
    __shared__ float red[16][6];
    int w = threadIdx.x >> 6;
    if ((threadIdx.x & 63) == 0) {
        red[w][0] = s0; red[w][1] = s1; red[w][2] = s2;
        red[w][3] = s3; red[w][4] = s4; red[w][5] = s5;
    }
    __syncthreads();
    if (threadIdx.x == 0) {
        float t0 = 0.f, t1 = 0.f, t2 = 0.f, t3 = 0.f, t4 = 0.f, t5 = 0.f;
        for (int i = 0; i < 16; ++i) {
            t0 += red[i][0]; t1 += red[i][1]; t2 += red[i][2];
            t3 += red[i][3]; t4 += red[i][4]; t5 += red[i][5];
        }
        float denf = t2 * 2.0f + 1e-6f;
        float denb = t3 * 2.0f + 1e-6f;
        float photo = t0 / denf + t1 / denb;
        float cens = t4 / denf + t5 / denb;
        out[0] = photo + cens;
        out[1] = photo;
        out[2] = cens;
    }
}

// ==================== Fallback: round-2 fused kernel (ws too small) ==========
#define LSTRF 73
__global__ __launch_bounds__(NT) void fused_fb_kernel(
        const float* __restrict__ img1, const float* __restrict__ img2,
        const float* __restrict__ ffw, const float* __restrict__ fbw,
        float* __restrict__ pacc, float* __restrict__ occ_out) {
    __shared__ float4 TILE[HY][LSTRF];
    __shared__ uchar2 MASKB[TY][TX];
    __shared__ unsigned short WORK[TY * TX];
    __shared__ int wcnt[16];
    __shared__ float red[8][6];

    const int img = blockIdx.x & 7;
    const int t = blockIdx.x >> 3;
    const int tyile = t / TILES_X;
    const int txile = t - tyile * TILES_X;
    const int gx0 = txile * TX - 3;
    const int gy0 = tyile * TY - 3;

    const float* i1 = img1 + img * 3 * HW;
    const float* i2 = img2 + img * 3 * HW;
    const float* f1 = ffw + img * 2 * HW;
    const float* f2 = fbw + img * 2 * HW;

    float s_pf = 0.f, s_pb = 0.f, s_mf = 0.f, s_mb = 0.f;

    for (int i = threadIdx.x; i < HX * HY; i += NT) {
        int ly = i / HX;
        int lx = i - ly * HX;
        int gx = gx0 + lx;
        int gy = gy0 + ly;
        bool inimg = (gx >= 0) & (gx < WW) & (gy >= 0) & (gy < HH);
        float v1 = 0.f, v2 = 0.f, v1w = 0.f, v2w = 0.f;
        if (inimg) {
            int p = gy * WW + gx;
            float fx = f1[p], fy = f1[HW + p];
            float bx = f2[p], by = f2[HW + p];
            float a0 = i1[p], a1 = i1[HW + p], a2 = i1[2 * HW + p];
            float c0 = i2[p], c1 = i2[HW + p], c2 = i2[2 * HW + p];

            FBil qf = fast_setup(fx, fy, gx, gy);
            FBil qb = fast_setup(bx, by, gx, gy);
            float w20 = fbil(i2, qf);
            float w21 = fbil(i2 + HW, qf);
            float w22 = fbil(i2 + 2 * HW, qf);
            float w10 = fbil(i1, qb);
            float w11 = fbil(i1 + HW, qb);
            float w12 = fbil(i1 + 2 * HW, qb);

            v1 = gray255(a0, a1, a2);
            v2 = gray255(c0, c1, c2);
            v2w = gray255(w20, w21, w22);
            v1w = gray255(w10, w11, w12);

            bool interior = (lx >= 3) & (lx < 3 + TX) & (ly >= 3) & (ly < 3 + TY);
            if (interior) {
                Bil sf = bilin_setup(fx, fy, gx, gy);
                Bil sb = bilin_setup(bx, by, gx, gy);
                float wbx = bilin(f2, sf), wby = bilin(f2 + HW, sf);
                float wfx = bilin(f1, sb), wfy = bilin(f1 + HW, sb);

                float dfx = fx + wbx, dfy = fy + wby;
                float magf = dfx * dfx + dfy * dfy;
                float fmf = fx * fx + fy * fy + wbx * wbx + wby * wby;
                float occf = (magf > 0.01f * fmf + 0.5f) ? 1.0f : 0.0f;
                float mf = 1.0f - occf;

                float dbx = bx + wfx, dby = by + wfy;
                float magb = dbx * dbx + dby * dby;
                float fmb = bx * bx + by * by + wfx * wfx + wfy * wfy;
                float occb = (magb > 0.01f * fmb + 0.5f) ? 1.0f : 0.0f;
                float mb = 1.0f - occb;

                MASKB[ly - 3][lx - 3] = make_uchar2((unsigned char)mf, (unsigned char)mb);
                occ_out[img * HW + p] = occf;

                s_pf += (robust04(a0 - w20) + robust04(a1 - w21) + robust04(a2 - w22)) * mf;
                s_pb += (robust04(c0 - w10) + robust04(c1 - w11) + robust04(c2 - w12)) * mb;
                s_mf += mf;
                s_mb += mb;
            }
        }
        TILE[ly][lx] = make_float4(v1, v2w, v2, v1w);
    }
    __syncthreads();

    const int lane = threadIdx.x & 63;
    const int wid = threadIdx.x >> 6;
    const unsigned long long lt = (1ull << lane) - 1ull;
    int ntot;
    {
        int pix0 = threadIdx.x;
        int pix1 = threadIdx.x + NT;
        uchar2 m0 = MASKB[pix0 >> 6][pix0 & 63];
        uchar2 m1 = MASKB[pix1 >> 6][pix1 & 63];
        bool l0 = (m0.x | m0.y) != 0;
        bool l1 = (m1.x | m1.y) != 0;
        unsigned long long b0 = __ballot(l0);
        unsigned long long b1 = __ballot(l1);
        if (lane == 0) {
            wcnt[wid] = __popcll(b0);
            wcnt[8 + wid] = __popcll(b1);
        }
        __syncthreads();
        int base0 = 0, base1 = 0;
        ntot = 0;
        for (int k = 0; k < 16; ++k) {
            int v = wcnt[k];
            if (k < wid) base0 += v;
            if (k < 8 + wid) base1 += v;
            ntot += v;
        }
        if (l0) WORK[base0 + __popcll(b0 & lt)] = (unsigned short)pix0;
        if (l1) WORK[base1 + __popcll(b1 & lt)] = (unsigned short)pix1;
        __syncthreads();
    }

    float s_cf = 0.f, s_cb = 0.f;
    for (int w = threadIdx.x; w < ntot; w += NT) {
        int pix = WORK[w];
        int r = pix >> 6, c = pix & 63;
        float4 C = TILE[3 + r][3 + c];
        float dsf = 0.f, dsb = 0.f;
#pragma unroll 1
        for (int dy = 0; dy < 7; ++dy) {
            const float4* prow = &TILE[r + dy][c];
#pragma unroll
            for (int dx = 0; dx < 7; ++dx) {
                float4 V = prow[dx];
                tap_eval4(V.x, V.y, V.z, V.w, C.x, C.y, C.z, C.w, dsf, dsb);
            }
        }
        uchar2 mm = MASKB[r][c];
        s_cf += robust04(dsf) * (float)mm.x;
        s_cb += robust04(dsb) * (float)mm.y;
    }

    for (int o = 32; o > 0; o >>= 1) {
        s_pf += __shfl_down(s_pf, o, 64);
        s_pb += __shfl_down(s_pb, o, 64);
        s_mf += __shfl_down(s_mf, o, 64);
        s_mb += __shfl_down(s_mb, o, 64);
        s_cf += __shfl_down(s_cf, o, 64);
        s_cb += __shfl_down(s_cb, o, 64);
    }
    if (lane == 0) {
        red[wid][0] = s_pf; red[wid][1] = s_pb;
        red[wid][2] = s_mf; red[wid][3] = s_mb;
        red[wid][4] = s_cf; red[wid][5] = s_cb;
    }
    __syncthreads();
    if (threadIdx.x == 0) {
        float r0 = 0.f, r1 = 0.f, r2 = 0.f, r3 = 0.f, r4 = 0.f, r5 = 0.f;
        for (int i = 0; i < 8; ++i) {
            r0 += red[i][0]; r1 += red[i][1]; r2 += red[i][2];
            r3 += red[i][3]; r4 += red[i][4]; r5 += red[i][5];
        }
        float* o = pacc + blockIdx.x * 6;
        o[0] = r0; o[1] = r1; o[2] = r2; o[3] = r3; o[4] = r4; o[5] = r5;
    }
}

__global__ __launch_bounds__(256) void finalize_fb_kernel(
        const float* __restrict__ pacc, float* __restrict__ out) {
    float s0 = 0.f, s1 = 0.f, s2 = 0.f, s3 = 0.f, s4 = 0.f, s5 = 0.f;
    for (int i = threadIdx.x; i < GRID2; i += 256) {
        const float* o = pacc + i * 6;
        s0 += o[0]; s1 += o[1]; s2 += o[2];
        s3 += o[3]; s4 += o[4]; s5 += o[5];
    }
    for (int o = 32; o > 0; o >>= 1) {
        s0 += __shfl_down(s0, o, 64);
        s1 += __shfl_down(s1, o, 64);
        s2 += __shfl_down(s2, o, 64);
        s3 += __shfl_down(s3, o, 64);
        s4 += __shfl_down(s4, o, 64);
        s5 += __shfl_down(s5, o, 64);
    }
    __shared__ float red[4][6];
    int w = threadIdx.x >> 6;
    if ((threadIdx.x & 63) == 0) {
        red[w][0] = s0; red[w][1] = s1; red[w][2] = s2;
        red[w][3] = s3; red[w][4] = s4; red[w][5] = s5;
    }
    __syncthreads();
    if (threadIdx.x == 0) {
        float t0 = 0.f, t1 = 0.f, t2 = 0.f, t3 = 0.f, t4 = 0.f, t5 = 0.f;
        for (int i = 0; i < 4; ++i) {
            t0 += red[i][0]; t1 += red[i][1]; t2 += red[i][2];
            t3 += red[i][3]; t4 += red[i][4]; t5 += red[i][5];
        }
        float denf = t2 * 2.0f + 1e-6f;
        float denb = t3 * 2.0f + 1e-6f;
        float photo = t0 / denf + t1 / denb;
        float cens = t4 / denf + t5 / denb;
        out[0] = photo + cens;
        out[1] = photo;
        out[2] = cens;
    }
}

extern "C" void kernel_launch(void* const* d_in, const int* in_sizes, int n_in,
                              void* d_out, int out_size, void* d_ws, size_t ws_size,
                              hipStream_t stream) {
    const float* img1 = (const float*)d_in[0];
    const float* img2 = (const float*)d_in[1];
    const float* ffw = (const float*)d_in[2];
    const float* fbw = (const float*)d_in[3];
    float* out = (float*)d_out;
    char* ws = (char*)d_ws;

    // workspace layout for the split path
    const size_t planes_off = 0;
    const size_t planes_sz = (size_t)NPIX * 8;            // Pair4
    const size_t masks_off = planes_off + planes_sz;
    const size_t masks_sz = (size_t)NPIX * 2;             // uchar2
    const size_t pacc1_off = masks_off + masks_sz;
    const size_t pacc1_sz = (size_t)NB1 * 4 * 4;
    const size_t pacc2_off = pacc1_off + pacc1_sz;
    const size_t pacc2_sz = (size_t)GRID2 * 2 * 4;
    const size_t need = pacc2_off + pacc2_sz;             // ~22.7 MB

    if (ws_size >= need) {
        Pair4* planes = (Pair4*)(ws + planes_off);
        uchar2* masks = (uchar2*)(ws + masks_off);
        float* pacc1 = (float*)(ws + pacc1_off);
        float* pacc2 = (float*)(ws + pacc2_off);
        // two half-grid k1 dispatches: puts k2 at the top of rocprof's
        // per-dispatch ranking so its counters become visible (r9 probe)
        k1_kernel<<<NB1H, 256, 0, stream>>>(img1, img2, ffw, fbw,
                                            planes, masks, pacc1, out + 3, 0);
        k1_kernel<<<NB1H, 256, 0, stream>>>(img1, img2, ffw, fbw,
                                            planes, masks, pacc1, out + 3, NB1H);
        k2_kernel<<<GRID2, K2T, 0, stream>>>(planes, masks, pacc2);
        finalize2_kernel<<<1, 1024, 0, stream>>>(pacc1, pacc2, out);
    } else {
        float* pacc = (float*)ws;   // GRID2*6 floats
        fused_fb_kernel<<<GRID2, NT, 0, stream>>>(img1, img2, ffw, fbw, pacc, out + 3);
        finalize_fb_kernel<<<1, 256, 0, stream>>>(pacc, out);
    }
}

// Round 11
// 211.774 us; speedup vs baseline: 1.0464x; 1.0464x over previous
//
#include <hip/hip_runtime.h>
#include <hip/hip_fp16.h>
#include <math.h>

#define BB 8
#define HH 384
#define WW 768
#define HW (HH * WW)
#define NPIX (BB * HW)       // 2359296

#define NT 512           // fallback fused kernel threads
#define K2T 128          // K2 threads per block (r11: 9 blocks/CU all-resident)
#define TX 64
#define TY 16
#define HX (TX + 6)      // 70
#define HY (TY + 6)      // 22
#define LP 72            // LDS plane row stride (uint2 elements)
#define TILES_X (WW / TX)            // 12
#define TILES_Y (HH / TY)            // 24
#define NTILE (TILES_X * TILES_Y)    // 288 per image
#define GRID2 (NTILE * BB)           // 2304
#define NB1 (NPIX / 256)             // 9216 K1 blocks (256 thr — round-6 winner)
#define K1TX 12                      // K1: 64x4 tiles, 12 x 96 per image

// 8-byte pair load with only 4-byte alignment guaranteed.
struct F2 { float x, y; };
__device__ __forceinline__ F2 ld2(const float* __restrict__ p) {
    return *(const F2*)p;
}

// ---------- exact bilinear (feeds binary occ -> must stay bit-stable) ----------
struct Bil { int x0, x1, y0, y1; float wx, wy; };

__device__ __forceinline__ Bil bilin_setup(float fx, float fy, int x, int y) {
    Bil s;
    float gx = fminf(fmaxf(fx + (float)x, 0.0f), (float)(WW - 1));
    float gy = fminf(fmaxf(fy + (float)y, 0.0f), (float)(HH - 1));
    float x0f = floorf(gx), y0f = floorf(gy);
    s.wx = gx - x0f;
    s.wy = gy - y0f;
    s.x0 = (int)x0f;
    s.y0 = (int)y0f;
    s.x1 = min(s.x0 + 1, WW - 1);
    s.y1 = min(s.y0 + 1, HH - 1);
    return s;
}

__device__ __forceinline__ float bilin(const float* __restrict__ pl, const Bil& s) {
    float v00 = pl[s.y0 * WW + s.x0];
    float v01 = pl[s.y0 * WW + s.x1];
    float v10 = pl[s.y1 * WW + s.x0];
    float v11 = pl[s.y1 * WW + s.x1];
    float iwx = 1.0f - s.wx, iwy = 1.0f - s.wy;
    return v00 * iwx * iwy + v01 * s.wx * iwy + v10 * iwx * s.wy + v11 * s.wx * s.wy;
}

// Paired-load bilin: BIT-IDENTICAL values to bilin() in all cases (r6 proof).
__device__ __forceinline__ float bilin2(const float* __restrict__ pl, const Bil& s) {
    int xb = min(s.x0, WW - 2);
    bool hi = s.x0 > xb;                       // only at the x==W-1 border
    F2 tp = ld2(pl + s.y0 * WW + xb);
    F2 bt = ld2(pl + s.y1 * WW + xb);
    float v00 = hi ? tp.y : tp.x;
    float v10 = hi ? bt.y : bt.x;
    float v01 = tp.y;
    float v11 = bt.y;
    float iwx = 1.0f - s.wx, iwy = 1.0f - s.wy;
    return v00 * iwx * iwy + v01 * s.wx * iwy + v10 * iwx * s.wy + v11 * s.wx * s.wy;
}

// ---------- fast bilinear (image gathers; loss-tolerant) ----------
struct FBil { int off; float wx, wy; };

__device__ __forceinline__ FBil fast_setup(float fx, float fy, int x, int y) {
    FBil s;
    float gx = fminf(fmaxf(fx + (float)x, 0.0f), (float)(WW - 1));
    float gy = fminf(fmaxf(fy + (float)y, 0.0f), (float)(HH - 1));
    int x0 = min((int)floorf(gx), WW - 2);
    int y0 = min((int)floorf(gy), HH - 2);
    s.wx = gx - (float)x0;
    s.wy = gy - (float)y0;
    s.off = y0 * WW + x0;
    return s;
}

__device__ __forceinline__ float fbil(const float* __restrict__ pl, const FBil& s) {
    const float* q = pl + s.off;
    float v00 = q[0], v01 = q[1], v10 = q[WW], v11 = q[WW + 1];
    float top = fmaf(s.wx, v01 - v00, v00);
    float bot = fmaf(s.wx, v11 - v10, v10);
    return fmaf(s.wy, bot - top, top);
}

// Paired-load fbil: identical arithmetic, 2 VMEM instead of 4.
__device__ __forceinline__ float fbil2(const float* __restrict__ pl, const FBil& s) {
    F2 t = ld2(pl + s.off);
    F2 b = ld2(pl + s.off + WW);
    float top = fmaf(s.wx, t.y - t.x, t.x);
    float bot = fmaf(s.wx, b.y - b.x, b.x);
    return fmaf(s.wy, bot - top, top);
}

__device__ __forceinline__ float gray255(float r, float g, float b) {
    return (0.2989f * r + 0.587f * g + 0.114f * b) * 255.0f;
}

__device__ __forceinline__ float robust04(float a) {
    // pow(|a| + 0.01, 0.4) via HW log2/exp2 (arg always > 0)
    float v = fabsf(a) + 0.01f;
    return __builtin_amdgcn_exp2f(0.4f * __builtin_amdgcn_logf(v));
}

struct __align__(8) Pair4 {
    __half2 fw;   // (inten1, inten2w)
    __half2 bw;   // (inten2, inten1w)
};

__device__ __forceinline__ float2 h2f(unsigned int u) {
    __half2 h;
    *reinterpret_cast<unsigned int*>(&h) = u;
    return __half22float2(h);
}

// Dual-stream census tap (used by the fallback fused kernel).
__device__ __forceinline__ void tap_eval4(float Vx, float Vy, float Vz, float Vw,
                                          float Cx, float Cy, float Cz, float Cw,
                                          float& dsf, float& dsb) {
    float u1 = Vx - Cx, u2 = Vy - Cy;
    float q1 = u1 * u1, q2 = u2 * u2;
    float a1 = q1 + 0.81f, a2 = q2 + 0.81f;
    float sf = __builtin_amdgcn_rsqf(a1 * a2);
    float hf = fmaf(q1, a2, q2 * a1);
    float d2f = fmaf(sf * sf, hf, -2.0f * ((u1 * u2) * sf));

    float w1 = Vz - Cz, w2 = Vw - Cw;
    float p1 = w1 * w1, p2 = w2 * w2;
    float b1 = p1 + 0.81f, b2 = p2 + 0.81f;
    float sb = __builtin_amdgcn_rsqf(b1 * b2);
    float hb = fmaf(p1, b2, p2 * b1);
    float d2b = fmaf(sb * sb, hb, -2.0f * ((w1 * w2) * sb));

    float denf = 0.1f + d2f, denb = 0.1f + d2b;
    float rr = __builtin_amdgcn_rcpf(denf * denb);
    dsf = fmaf(d2f * denb, rr, dsf);
    dsb = fmaf(d2b * denf, rr, dsb);
}

// ==================== K1: per-pixel warp/photo/occ, plane production ==========
// 1 px/thread, 64x4 tiles, 256-thread blocks (round-6 winner: 71.5 us;
// 2px/thread, 1024-thread, and split-dispatch variants all regressed).
// img = blockIdx&7 keeps image<->XCD affinity (round-4: FETCH 300->46 MB);
// paired 8B corner loads (round 6). pacc1 layout per block: [pf, pb, mf, mb]
__global__ __launch_bounds__(256) void k1_kernel(
        const float* __restrict__ img1, const float* __restrict__ img2,
        const float* __restrict__ ffw, const float* __restrict__ fbw,
        Pair4* __restrict__ planes, uchar2* __restrict__ masks,
        float* __restrict__ pacc1, float* __restrict__ occ_out) {
    const int img = blockIdx.x & 7;
    const int t = blockIdx.x >> 3;            // 0..1151
    const int tyy = t / K1TX;                 // 4-row band 0..95
    const int txx = t - tyy * K1TX;
    const int x = txx * 64 + (threadIdx.x & 63);
    const int y = tyy * 4 + (threadIdx.x >> 6);
    const int p = y * WW + x;
    const int g = img * HW + p;

    const float* i1 = img1 + img * 3 * HW;
    const float* i2 = img2 + img * 3 * HW;
    const float* f1 = ffw + img * 2 * HW;
    const float* f2 = fbw + img * 2 * HW;

    float fx = f1[p], fy = f1[HW + p];
    float bx = f2[p], by = f2[HW + p];
    float a0 = i1[p], a1 = i1[HW + p], a2 = i1[2 * HW + p];
    float c0 = i2[p], c1 = i2[HW + p], c2 = i2[2 * HW + p];

    // image gathers: fast shared-base path (feeds losses only)
    FBil qf = fast_setup(fx, fy, x, y);
    FBil qb = fast_setup(bx, by, x, y);
    float w20 = fbil2(i2, qf);
    float w21 = fbil2(i2 + HW, qf);
    float w22 = fbil2(i2 + 2 * HW, qf);
    float w10 = fbil2(i1, qb);
    float w11 = fbil2(i1 + HW, qb);
    float w12 = fbil2(i1 + 2 * HW, qb);

    float v1 = gray255(a0, a1, a2);
    float v2 = gray255(c0, c1, c2);
    float v2w = gray255(w20, w21, w22);
    float v1w = gray255(w10, w11, w12);

    // flow gathers: exact path (feeds binary occ)
    Bil sf = bilin_setup(fx, fy, x, y);
    Bil sb = bilin_setup(bx, by, x, y);
    float wbx = bilin2(f2, sf), wby = bilin2(f2 + HW, sf);
    float wfx = bilin2(f1, sb), wfy = bilin2(f1 + HW, sb);

    float dfx = fx + wbx, dfy = fy + wby;
    float magf = dfx * dfx + dfy * dfy;
    float fmf = fx * fx + fy * fy + wbx * wbx + wby * wby;
    float occf = (magf > 0.01f * fmf + 0.5f) ? 1.0f : 0.0f;
    float mf = 1.0f - occf;

    float dbx = bx + wfx, dby = by + wfy;
    float magb = dbx * dbx + dby * dby;
    float fmb = bx * bx + by * by + wfx * wfx + wfy * wfy;
    float occb = (magb > 0.01f * fmb + 0.5f) ? 1.0f : 0.0f;
    float mb = 1.0f - occb;

    occ_out[g] = occf;
    masks[g] = make_uchar2((unsigned char)mf, (unsigned char)mb);
    Pair4 pr;
    pr.fw = __floats2half2_rn(v1, v2w);
    pr.bw = __floats2half2_rn(v2, v1w);
    planes[g] = pr;

    float s_pf = (robust04(a0 - w20) + robust04(a1 - w21) + robust04(a2 - w22)) * mf;
    float s_pb = (robust04(c0 - w10) + robust04(c1 - w11) + robust04(c2 - w12)) * mb;

    // block reduce 4 partials (4 waves)
    float s_mf = mf, s_mb = mb;
    for (int o = 32; o > 0; o >>= 1) {
        s_pf += __shfl_down(s_pf, o, 64);
        s_pb += __shfl_down(s_pb, o, 64);
        s_mf += __shfl_down(s_mf, o, 64);
        s_mb += __shfl_down(s_mb, o, 64);
    }
    __shared__ float red[4][4];
    const int wid = threadIdx.x >> 6;
    if ((threadIdx.x & 63) == 0) {
        red[wid][0] = s_pf; red[wid][1] = s_pb;
        red[wid][2] = s_mf; red[wid][3] = s_mb;
    }
    __syncthreads();
    if (threadIdx.x == 0) {
        float r0 = 0.f, r1 = 0.f, r2 = 0.f, r3 = 0.f;
        for (int i = 0; i < 4; ++i) {
            r0 += red[i][0]; r1 += red[i][1]; r2 += red[i][2]; r3 += red[i][3];
        }
        float* o = pacc1 + blockIdx.x * 4;
        o[0] = r0; o[1] = r1; o[2] = r2; o[3] = r3;
    }
}

// ==================== K2: census over live pixels ============================
// r11: STREAM-SPLIT worklist — with mask rates ~0.15 each, ~92% of live
// pixels need only ONE of the fw/bw streams; enumerate (pixel,stream) pairs
// (fw entries then bw entries, sorted -> wave-coherent) and evaluate a single
// stream per entry: ~45% less census VALU (r10: VALU-issue-bound at 61%).
// Per-stream tap math = round-0-validated rcp(0.1+d2) form.
// 128-thread blocks: LDS ~16.9KB x 9 blocks/CU fits -> all 9 blocks resident
// (r10: 256-thr blocks capped at 8/CU -> 9th block ran alone, 2x makespan).
// pacc2 layout per block: [cf, cb]
__global__ __launch_bounds__(K2T) void k2_kernel(
        const Pair4* __restrict__ planes, const uchar2* __restrict__ masks,
        float* __restrict__ pacc2) {
    __shared__ uint2 PP[HY][LP];              // (fw bits, bw bits), 12.7 KB
    __shared__ unsigned short WORK[2 * TY * TX];  // fw entries then bw entries
    __shared__ int wcntF[16], wcntB[16];      // [segment 0..7][wave 0..1]
    __shared__ float red[2][2];

    const int img = blockIdx.x & 7;
    const int t = blockIdx.x >> 3;
    const int tyile = t / TILES_X;
    const int txile = t - tyile * TILES_X;
    const int gx0 = txile * TX - 3;
    const int gy0 = tyile * TY - 3;

    // ---- stage planes (coalesced 8B loads, direct uint2 LDS writes) ----
    const uint2* pl2 = (const uint2*)planes;
    for (int i = threadIdx.x; i < HX * HY; i += K2T) {
        int ly = i / HX;
        int lx = i - ly * HX;
        int gx = gx0 + lx;
        int gy = gy0 + ly;
        uint2 pr8 = make_uint2(0u, 0u);
        if (((unsigned)gx < (unsigned)WW) & ((unsigned)gy < (unsigned)HH)) {
            pr8 = pl2[img * HW + gy * WW + gx];
        }
        PP[ly][lx] = pr8;
    }
    __syncthreads();

    // ---- (pixel,stream) compaction: 8 segments x 2 waves, ballot prefix ----
    const int lane = threadIdx.x & 63;
    const int wid = threadIdx.x >> 6;           // 0..1
    const unsigned long long lt = (1ull << lane) - 1ull;
    const int grow = img * HW + (tyile * TY) * WW + txile * TX;   // g of tile (0,0)
    int ntot;
    {
        bool lf[8], lb[8];
        unsigned long long bf[8], bb[8];
#pragma unroll
        for (int sg = 0; sg < 8; ++sg) {
            int pix = sg * K2T + threadIdx.x;
            uchar2 m = masks[grow + (pix >> 6) * WW + (pix & 63)];
            lf[sg] = m.x != 0;
            lb[sg] = m.y != 0;
            bf[sg] = __ballot(lf[sg]);
            bb[sg] = __ballot(lb[sg]);
            if (lane == 0) {
                wcntF[sg * 2 + wid] = __popcll(bf[sg]);
                wcntB[sg * 2 + wid] = __popcll(bb[sg]);
            }
        }
        __syncthreads();
        int baseF[8] = {0, 0, 0, 0, 0, 0, 0, 0};
        int baseB[8] = {0, 0, 0, 0, 0, 0, 0, 0};
        int nF = 0, nB = 0;
        for (int k = 0; k < 16; ++k) {
            int vF = wcntF[k], vB = wcntB[k];
#pragma unroll
            for (int sg = 0; sg < 8; ++sg) {
                if (k < sg * 2 + wid) { baseF[sg] += vF; baseB[sg] += vB; }
            }
            nF += vF; nB += vB;
        }
#pragma unroll
        for (int sg = 0; sg < 8; ++sg) {
            int pix = sg * K2T + threadIdx.x;
            if (lf[sg]) WORK[baseF[sg] + __popcll(bf[sg] & lt)] = (unsigned short)pix;
            if (lb[sg]) WORK[nF + baseB[sg] + __popcll(bb[sg] & lt)] =
                (unsigned short)(pix | 0x400);
        }
        ntot = nF + nB;
        __syncthreads();
    }

    // ---- 49-tap census: single stream per entry, 1 ds_read_b64 per tap ----
    float s_cf = 0.f, s_cb = 0.f;
    for (int w = threadIdx.x; w < ntot; w += K2T) {
        int e = WORK[w];
        int pix = e & 1023;
        bool isbw = (e & 0x400) != 0;
        int r = pix >> 6, c = pix & 63;
        uint2 C2 = PP[3 + r][3 + c];
        float2 cf = h2f(isbw ? C2.y : C2.x);
        float ds = 0.f;
#pragma unroll 1
        for (int dy = 0; dy < 7; ++dy) {
            const uint2* row = &PP[r + dy][c];
#pragma unroll
            for (int dx = 0; dx < 7; ++dx) {
                uint2 V2 = row[dx];
                float2 vf = h2f(isbw ? V2.y : V2.x);
                float u1 = vf.x - cf.x, u2 = vf.y - cf.y;
                float q1 = u1 * u1, q2 = u2 * u2;
                float a1 = q1 + 0.81f, a2 = q2 + 0.81f;
                float s = __builtin_amdgcn_rsqf(a1 * a2);
                float h = fmaf(q1, a2, q2 * a1);
                float d2 = fmaf(s * s, h, -2.0f * ((u1 * u2) * s));
                ds = fmaf(d2, __builtin_amdgcn_rcpf(0.1f + d2), ds);
            }
        }
        float rv = robust04(ds);
        if (isbw) s_cb += rv; else s_cf += rv;
    }

    // ---- reduce 2 partials across 2 waves ----
    for (int o = 32; o > 0; o >>= 1) {
        s_cf += __shfl_down(s_cf, o, 64);
        s_cb += __shfl_down(s_cb, o, 64);
    }
    if (lane == 0) {
        red[wid][0] = s_cf; red[wid][1] = s_cb;
    }
    __syncthreads();
    if (threadIdx.x == 0) {
        float* o = pacc2 + blockIdx.x * 2;
        o[0] = red[0][0] + red[1][0];
        o[1] = red[0][1] + red[1][1];
    }
}

__global__ __launch_bounds__(1024) void finalize2_kernel(
        const float* __restrict__ pacc1, const float* __restrict__ pacc2,
        float* __restrict__ out) {
    float s0 = 0.f, s1 = 0.f, s2 = 0.f, s3 = 0.f, s4 = 0.f, s5 = 0.f;
    for (int i = threadIdx.x; i < NB1; i += 1024) {
        const float* o = pacc1 + i * 4;
        s0 += o[0]; s1 += o[1]; s2 += o[2]; s3 += o[3];
    }
    for (int i = threadIdx.x; i < GRID2; i += 1024) {
        const float* o = pacc2 + i * 2;
        s4 += o[0]; s5 += o[1];
    }
    for (int o = 32; o > 0; o >>= 1) {
        s0 += __shfl_down(s0, o, 64);
        s1 += __shfl_down(s1, o, 64);
        s2 += __shfl_down(s2, o, 64);
        s3 += __shfl_down(s3, o, 64);
        s4 += __shfl_down(s4, o, 64);
        s5 += __shfl_down(s5, o, 64);
    }
    __shared__ float red[16][6];
    int w = threadIdx.x >> 6;
    if ((threadIdx.x & 63) == 0) {
        red[w][0] = s0; red[w][1] = s1; red[w][2] = s2;
        red[w][3] = s3; red[w][4] = s4; red[w][5] = s5;
    }
    __syncthreads();
    if (threadIdx.x == 0) {
        float t0 = 0.f, t1 = 0.f, t2 = 0.f, t3 = 0.f, t4 = 0.f, t5 = 0.f;
        for (int i = 0; i < 16; ++i) {
            t0 += red[i][0]; t1 += red[i][1]; t2 += red[i][2];
            t3 += red[i][3]; t4 += red[i][4]; t5 += red[i][5];
        }
        float denf = t2 * 2.0f + 1e-6f;
        float denb = t3 * 2.0f + 1e-6f;
        float photo = t0 / denf + t1 / denb;
        float cens = t4 / denf + t5 / denb;
        out[0] = photo + cens;
        out[1] = photo;
        out[2] = cens;
    }
}

// ==================== Fallback: round-2 fused kernel (ws too small) ==========
#define LSTRF 73
__global__ __launch_bounds__(NT) void fused_fb_kernel(
        const float* __restrict__ img1, const float* __restrict__ img2,
        const float* __restrict__ ffw, const float* __restrict__ fbw,
        float* __restrict__ pacc, float* __restrict__ occ_out) {
    __shared__ float4 TILE[HY][LSTRF];
    __shared__ uchar2 MASKB[TY][TX];
    __shared__ unsigned short WORK[TY * TX];
    __shared__ int wcnt[16];
    __shared__ float red[8][6];

    const int img = blockIdx.x & 7;
    const int t = blockIdx.x >> 3;
    const int tyile = t / TILES_X;
    const int txile = t - tyile * TILES_X;
    const int gx0 = txile * TX - 3;
    const int gy0 = tyile * TY - 3;

    const float* i1 = img1 + img * 3 * HW;
    const float* i2 = img2 + img * 3 * HW;
    const float* f1 = ffw + img * 2 * HW;
    const float* f2 = fbw + img * 2 * HW;

    float s_pf = 0.f, s_pb = 0.f, s_mf = 0.f, s_mb = 0.f;

    for (int i = threadIdx.x; i < HX * HY; i += NT) {
        int ly = i / HX;
        int lx = i - ly * HX;
        int gx = gx0 + lx;
        int gy = gy0 + ly;
        bool inimg = (gx >= 0) & (gx < WW) & (gy >= 0) & (gy < HH);
        float v1 = 0.f, v2 = 0.f, v1w = 0.f, v2w = 0.f;
        if (inimg) {
            int p = gy * WW + gx;
            float fx = f1[p], fy = f1[HW + p];
            float bx = f2[p], by = f2[HW + p];
            float a0 = i1[p], a1 = i1[HW + p], a2 = i1[2 * HW + p];
            float c0 = i2[p], c1 = i2[HW + p], c2 = i2[2 * HW + p];

            FBil qf = fast_setup(fx, fy, gx, gy);
            FBil qb = fast_setup(bx, by, gx, gy);
            float w20 = fbil(i2, qf);
            float w21 = fbil(i2 + HW, qf);
            float w22 = fbil(i2 + 2 * HW, qf);
            float w10 = fbil(i1, qb);
            float w11 = fbil(i1 + HW, qb);
            float w12 = fbil(i1 + 2 * HW, qb);

            v1 = gray255(a0, a1, a2);
            v2 = gray255(c0, c1, c2);
            v2w = gray255(w20, w21, w22);
            v1w = gray255(w10, w11, w12);

            bool interior = (lx >= 3) & (lx < 3 + TX) & (ly >= 3) & (ly < 3 + TY);
            if (interior) {
                Bil sf = bilin_setup(fx, fy, gx, gy);
                Bil sb = bilin_setup(bx, by, gx, gy);
                float wbx = bilin(f2, sf), wby = bilin(f2 + HW, sf);
                float wfx = bilin(f1, sb), wfy = bilin(f1 + HW, sb);

                float dfx = fx + wbx, dfy = fy + wby;
                float magf = dfx * dfx + dfy * dfy;
                float fmf = fx * fx + fy * fy + wbx * wbx + wby * wby;
                float occf = (magf > 0.01f * fmf + 0.5f) ? 1.0f : 0.0f;
                float mf = 1.0f - occf;

                float dbx = bx + wfx, dby = by + wfy;
                float magb = dbx * dbx + dby * dby;
                float fmb = bx * bx + by * by + wfx * wfx + wfy * wfy;
                float occb = (magb > 0.01f * fmb + 0.5f) ? 1.0f : 0.0f;
                float mb = 1.0f - occb;

                MASKB[ly - 3][lx - 3] = make_uchar2((unsigned char)mf, (unsigned char)mb);
                occ_out[img * HW + p] = occf;

                s_pf += (robust04(a0 - w20) + robust04(a1 - w21) + robust04(a2 - w22)) * mf;
                s_pb += (robust04(c0 - w10) + robust04(c1 - w11) + robust04(c2 - w12)) * mb;
                s_mf += mf;
                s_mb += mb;
            }
        }
        TILE[ly][lx] = make_float4(v1, v2w, v2, v1w);
    }
    __syncthreads();

    const int lane = threadIdx.x & 63;
    const int wid = threadIdx.x >> 6;
    const unsigned long long lt = (1ull << lane) - 1ull;
    int ntot;
    {
        int pix0 = threadIdx.x;
        int pix1 = threadIdx.x + NT;
        uchar2 m0 = MASKB[pix0 >> 6][pix0 & 63];
        uchar2 m1 = MASKB[pix1 >> 6][pix1 & 63];
        bool l0 = (m0.x | m0.y) != 0;
        bool l1 = (m1.x | m1.y) != 0;
        unsigned long long b0 = __ballot(l0);
        unsigned long long b1 = __ballot(l1);
        if (lane == 0) {
            wcnt[wid] = __popcll(b0);
            wcnt[8 + wid] = __popcll(b1);
        }
        __syncthreads();
        int base0 = 0, base1 = 0;
        ntot = 0;
        for (int k = 0; k < 16; ++k) {
            int v = wcnt[k];
            if (k < wid) base0 += v;
            if (k < 8 + wid) base1 += v;
            ntot += v;
        }
        if (l0) WORK[base0 + __popcll(b0 & lt)] = (unsigned short)pix0;
        if (l1) WORK[base1 + __popcll(b1 & lt)] = (unsigned short)pix1;
        __syncthreads();
    }

    float s_cf = 0.f, s_cb = 0.f;
    for (int w = threadIdx.x; w < ntot; w += NT) {
        int pix = WORK[w];
        int r = pix >> 6, c = pix & 63;
        float4 C = TILE[3 + r][3 + c];
        float dsf = 0.f, dsb = 0.f;
#pragma unroll 1
        for (int dy = 0; dy < 7; ++dy) {
            const float4* prow = &TILE[r + dy][c];
#pragma unroll
            for (int dx = 0; dx < 7; ++dx) {
                float4 V = prow[dx];
                tap_eval4(V.x, V.y, V.z, V.w, C.x, C.y, C.z, C.w, dsf, dsb);
            }
        }
        uchar2 mm = MASKB[r][c];
        s_cf += robust04(dsf) * (float)mm.x;
        s_cb += robust04(dsb) * (float)mm.y;
    }

    for (int o = 32; o > 0; o >>= 1) {
        s_pf += __shfl_down(s_pf, o, 64);
        s_pb += __shfl_down(s_pb, o, 64);
        s_mf += __shfl_down(s_mf, o, 64);
        s_mb += __shfl_down(s_mb, o, 64);
        s_cf += __shfl_down(s_cf, o, 64);
        s_cb += __shfl_down(s_cb, o, 64);
    }
    if (lane == 0) {
        red[wid][0] = s_pf; red[wid][1] = s_pb;
        red[wid][2] = s_mf; red[wid][3] = s_mb;
        red[wid][4] = s_cf; red[wid][5] = s_cb;
    }
    __syncthreads();
    if (threadIdx.x == 0) {
        float r0 = 0.f, r1 = 0.f, r2 = 0.f, r3 = 0.f, r4 = 0.f, r5 = 0.f;
        for (int i = 0; i < 8; ++i) {
            r0 += red[i][0]; r1 += red[i][1]; r2 += red[i][2];
            r3 += red[i][3]; r4 += red[i][4]; r5 += red[i][5];
        }
        float* o = pacc + blockIdx.x * 6;
        o[0] = r0; o[1] = r1; o[2] = r2; o[3] = r3; o[4] = r4; o[5] = r5;
    }
}

__global__ __launch_bounds__(256) void finalize_fb_kernel(
        const float* __restrict__ pacc, float* __restrict__ out) {
    float s0 = 0.f, s1 = 0.f, s2 = 0.f, s3 = 0.f, s4 = 0.f, s5 = 0.f;
    for (int i = threadIdx.x; i < GRID2; i += 256) {
        const float* o = pacc + i * 6;
        s0 += o[0]; s1 += o[1]; s2 += o[2];
        s3 += o[3]; s4 += o[4]; s5 += o[5];
    }
    for (int o = 32; o > 0; o >>= 1) {
        s0 += __shfl_down(s0, o, 64);
        s1 += __shfl_down(s1, o, 64);
        s2 += __shfl_down(s2, o, 64);
        s3 += __shfl_down(s3, o, 64);
        s4 += __shfl_down(s4, o, 64);
        s5 += __shfl_down(s5, o, 64);
    }
    __shared__ float red[4][6];
    int w = threadIdx.x >> 6;
    if ((threadIdx.x & 63) == 0) {
        red[w][0] = s0; red[w][1] = s1; red[w][2] = s2;
        red[w][3] = s3; red[w][4] = s4; red[w][5] = s5;
    }
    __syncthreads();
    if (threadIdx.x == 0) {
        float t0 = 0.f, t1 = 0.f, t2 = 0.f, t3 = 0.f, t4 = 0.f, t5 = 0.f;
        for (int i = 0; i < 4; ++i) {
            t0 += red[i][0]; t1 += red[i][1]; t2 += red[i][2];
            t3 += red[i][3]; t4 += red[i][4]; t5 += red[i][5];
        }
        float denf = t2 * 2.0f + 1e-6f;
        float denb = t3 * 2.0f + 1e-6f;
        float photo = t0 / denf + t1 / denb;
        float cens = t4 / denf + t5 / denb;
        out[0] = photo + cens;
        out[1] = photo;
        out[2] = cens;
    }
}

extern "C" void kernel_launch(void* const* d_in, const int* in_sizes, int n_in,
                              void* d_out, int out_size, void* d_ws, size_t ws_size,
                              hipStream_t stream) {
    const float* img1 = (const float*)d_in[0];
    const float* img2 = (const float*)d_in[1];
    const float* ffw = (const float*)d_in[2];
    const float* fbw = (const float*)d_in[3];
    float* out = (float*)d_out;
    char* ws = (char*)d_ws;

    // workspace layout for the split path
    const size_t planes_off = 0;
    const size_t planes_sz = (size_t)NPIX * 8;            // Pair4
    const size_t masks_off = planes_off + planes_sz;
    const size_t masks_sz = (size_t)NPIX * 2;             // uchar2
    const size_t pacc1_off = masks_off + masks_sz;
    const size_t pacc1_sz = (size_t)NB1 * 4 * 4;
    const size_t pacc2_off = pacc1_off + pacc1_sz;
    const size_t pacc2_sz = (size_t)GRID2 * 2 * 4;
    const size_t need = pacc2_off + pacc2_sz;             // ~22.7 MB

    if (ws_size >= need) {
        Pair4* planes = (Pair4*)(ws + planes_off);
        uchar2* masks = (uchar2*)(ws + masks_off);
        float* pacc1 = (float*)(ws + pacc1_off);
        float* pacc2 = (float*)(ws + pacc2_off);
        k1_kernel<<<NB1, 256, 0, stream>>>(img1, img2, ffw, fbw,
                                           planes, masks, pacc1, out + 3);
        k2_kernel<<<GRID2, K2T, 0, stream>>>(planes, masks, pacc2);
        finalize2_kernel<<<1, 1024, 0, stream>>>(pacc1, pacc2, out);
    } else {
        float* pacc = (float*)ws;   // GRID2*6 floats
        fused_fb_kernel<<<GRID2, NT, 0, stream>>>(img1, img2, ffw, fbw, pacc, out + 3);
        finalize_fb_kernel<<<1, 256, 0, stream>>>(pacc, out);
    }
}